// Round 19
// baseline (43.682 us; speedup 1.0000x reference)
//
#include <hip/hip_runtime.h>

#define BATCH 128
#define LEN 512
#define N_OUT 10
#define SIG_DIM 4680
// canonical (thin) sig offsets -- used for W indexing only
#define OFF2W 8
#define OFF3W 72
#define OFF4W 584
// FATPAD LDS signature buffer: B1[8] | B2[64] | B3[64x9 pad] | B4[64x65 pad]
#define B2OFF 8
#define B3OFF 72
#define B4OFF 648
#define BUFSZ 4808

typedef float v4f __attribute__((ext_vector_type(4)));

// stage a fat-layout signature (thread lane=(i,j) owns s2, s3[k], s4[k][l])
// into a FATPAD LDS buffer. Strides 9/65 give <=2-way bank conflicts.
// [R16-verified]
__device__ __forceinline__ void stage_fat(float* __restrict__ buf,
                                          float s1, float s2,
                                          const float s3[8], const float s4[8][8],
                                          int lane) {
    if ((lane & 7) == 0) buf[lane >> 3] = s1;          // B1[i] (j==0 canonical)
    buf[B2OFF + lane] = s2;                            // B2[ij]
    #pragma unroll
    for (int k = 0; k < 8; ++k) buf[B3OFF + lane * 9 + k] = s3[k];
    #pragma unroll
    for (int k = 0; k < 8; ++k) {
        #pragma unroll
        for (int l = 0; l < 8; ++l)
            buf[B4OFF + lane * 65 + k * 8 + l] = s4[k][l];
    }
}

// Chen combine in fat layout: A (regs, earlier chunk) ∘= B (FATPAD LDS).
// [R16-verified]
__device__ __forceinline__ void combine_fat(float& A1, float& A2,
                                            float A3[8], float A4[8][8],
                                            const float* __restrict__ buf,
                                            int i, int j, int lane) {
    float B1[8];
    #pragma unroll
    for (int l = 0; l < 8; ++l) B1[l] = buf[l];
    // C4 = A4 + A3⊗B1 + A2⊗B2 + A1⊗B3 + B4   (old A1..A3)
    #pragma unroll
    for (int k = 0; k < 8; ++k) {
        #pragma unroll
        for (int l = 0; l < 8; ++l) {
            A4[k][l] += A3[k] * B1[l]
                      + A2 * buf[B2OFF + k * 8 + l]
                      + A1 * buf[B3OFF + (j * 8 + k) * 9 + l]
                      + buf[B4OFF + lane * 65 + k * 8 + l];
        }
    }
    // C3 = A3 + A2⊗B1 + A1⊗B2 + B3
    #pragma unroll
    for (int k = 0; k < 8; ++k) {
        A3[k] += A2 * B1[k]
               + A1 * buf[B2OFF + j * 8 + k]
               + buf[B3OFF + lane * 9 + k];
    }
    // C2 = A2 + A1⊗B1 + B2
    A2 += A1 * B1[j] + buf[B2OFF + lane];
    // C1
    A1 += B1[i];
}

// ---------------------------------------------------------------------------
// Single fused kernel: one block per batch element, 1024 threads = 16 waves.
// __launch_bounds__(1024, 4): min 4 waves/EU -> VGPR cap 128 (scan needs ~88;
// R17's regression was the default cap of 64 -> scratch spill).
// Phase 0: dx -> LDS. Phase 1: 16 waves x 32-step fat scan. Phase 2: 4-level
// in-block Chen tree via 4 FATPAD buffers. Phase 3: fused linear + reduce.
// ---------------------------------------------------------------------------
__global__ __launch_bounds__(1024, 4) void sig_fused_kernel(const float* __restrict__ X,
                                                            const float* __restrict__ W,
                                                            const float* __restrict__ bias,
                                                            float* __restrict__ out) {
    const int b = blockIdx.x;
    const int t = threadIdx.x;
    const int w = t >> 6;           // wave id == chunk id (0..15)
    const int lane = t & 63;        // (i,j)
    const int i = lane >> 3, j = lane & 7;

    __shared__ __align__(16) float lds[4 * BUFSZ];     // 75.1 KB (dx reuses it)
    __shared__ float red[8][N_OUT];

    // ---- Phase 0: dx[s][c] = X[s+1][c]-X[s][c] into lds[0..4095], row 511 = 0
    {
        const float2* __restrict__ X2 = (const float2*)(X + (size_t)b * LEN * 8);
        float2* __restrict__ d2 = (float2*)lds;
        #pragma unroll
        for (int p = 0; p < 2; ++p) {
            const int q = t + p * 1024;                // float2 index 0..2047
            const int s = q >> 2;
            float2 r = make_float2(0.f, 0.f);
            if (s < LEN - 1) {
                const float2 a = X2[q], c = X2[q + 4];
                r = make_float2(c.x - a.x, c.y - a.y);
            }
            d2[q] = r;
        }
    }
    __syncthreads();

    // ---- Phase 1: fat scan; wave w scans chunk w (32 steps; wave 15: 31)
    float s1 = 0.f, s2 = 0.f;
    float s3[8] = {};
    float s4[8][8] = {};
    {
        const int s0 = w * 32;
        const int nst = (w == 15) ? 31 : 32;           // avoid X[512] OOB
        const v4f* __restrict__ Xv = (const v4f*)(X + (size_t)b * LEN * 8);
        v4f pA = Xv[s0 * 2], pB = Xv[s0 * 2 + 1];
        const v4f* __restrict__ Xn = Xv + (s0 + 1) * 2;
        const float* __restrict__ dxL = lds + s0 * 8;
        #pragma unroll 4
        for (int s = 0; s < nst; ++s) {
            const v4f cA = Xn[s * 2], cB = Xn[s * 2 + 1];   // uniform VMEM
            const v4f dA = cA - pA, dB = cB - pB;
            pA = cA; pB = cB;
            const float vi = dxL[s * 8 + i];           // LDS broadcast (8 banks)
            const float vj = dxL[s * 8 + j];
            const float dv[8] = {dA.x, dA.y, dA.z, dA.w, dB.x, dB.y, dB.z, dB.w};

            const float t1 = s1 * vj;
            const float p  = vi * vj;
            const float u  = fmaf(1.f / 24.f, p, fmaf(1.f / 6.f, t1, 0.5f * s2));
            const float ww = fmaf(1.f / 6.f, p, fmaf(0.5f, t1, s2));
            float cc[8];
            #pragma unroll
            for (int k = 0; k < 8; ++k) {
                cc[k] = fmaf(dv[k], u, s3[k]);
                s3[k] = fmaf(dv[k], ww, s3[k]);
            }
            #pragma unroll
            for (int k = 0; k < 8; ++k) {
                #pragma unroll
                for (int l = 0; l < 8; ++l)
                    s4[k][l] = fmaf(cc[k], dv[l], s4[k][l]);
            }
            s2 = fmaf(0.5f, p, s2 + t1);
            s1 += vi;
        }
    }
    __syncthreads();            // dx region dead; lds becomes 4 sig buffers

    float* __restrict__ buf0 = lds;
    float* __restrict__ buf1 = lds + BUFSZ;
    float* __restrict__ buf2 = lds + 2 * BUFSZ;
    float* __restrict__ buf3 = lds + 3 * BUFSZ;

    // ---- Phase 2: 4-level pairwise Chen tree (A = earlier chunk always)
    // L1 round A: chunks 1,3,5,7 -> bufs; chunks 0,2,4,6 combine
    if (w == 1) stage_fat(buf0, s1, s2, s3, s4, lane);
    if (w == 3) stage_fat(buf1, s1, s2, s3, s4, lane);
    if (w == 5) stage_fat(buf2, s1, s2, s3, s4, lane);
    if (w == 7) stage_fat(buf3, s1, s2, s3, s4, lane);
    __syncthreads();
    if (w == 0) combine_fat(s1, s2, s3, s4, buf0, i, j, lane);
    if (w == 2) combine_fat(s1, s2, s3, s4, buf1, i, j, lane);
    if (w == 4) combine_fat(s1, s2, s3, s4, buf2, i, j, lane);
    if (w == 6) combine_fat(s1, s2, s3, s4, buf3, i, j, lane);
    __syncthreads();
    // L1 round B: chunks 9,11,13,15 -> bufs; chunks 8,10,12,14 combine
    if (w == 9)  stage_fat(buf0, s1, s2, s3, s4, lane);
    if (w == 11) stage_fat(buf1, s1, s2, s3, s4, lane);
    if (w == 13) stage_fat(buf2, s1, s2, s3, s4, lane);
    if (w == 15) stage_fat(buf3, s1, s2, s3, s4, lane);
    __syncthreads();
    if (w == 8)  combine_fat(s1, s2, s3, s4, buf0, i, j, lane);
    if (w == 10) combine_fat(s1, s2, s3, s4, buf1, i, j, lane);
    if (w == 12) combine_fat(s1, s2, s3, s4, buf2, i, j, lane);
    if (w == 14) combine_fat(s1, s2, s3, s4, buf3, i, j, lane);
    __syncthreads();
    // L2: pairs at waves 0,2,4,...,14
    if (w == 2)  stage_fat(buf0, s1, s2, s3, s4, lane);
    if (w == 6)  stage_fat(buf1, s1, s2, s3, s4, lane);
    if (w == 10) stage_fat(buf2, s1, s2, s3, s4, lane);
    if (w == 14) stage_fat(buf3, s1, s2, s3, s4, lane);
    __syncthreads();
    if (w == 0)  combine_fat(s1, s2, s3, s4, buf0, i, j, lane);
    if (w == 4)  combine_fat(s1, s2, s3, s4, buf1, i, j, lane);
    if (w == 8)  combine_fat(s1, s2, s3, s4, buf2, i, j, lane);
    if (w == 12) combine_fat(s1, s2, s3, s4, buf3, i, j, lane);
    __syncthreads();
    // L3: quads at waves 0,4,8,12
    if (w == 4)  stage_fat(buf0, s1, s2, s3, s4, lane);
    if (w == 12) stage_fat(buf1, s1, s2, s3, s4, lane);
    __syncthreads();
    if (w == 0) combine_fat(s1, s2, s3, s4, buf0, i, j, lane);
    if (w == 8) combine_fat(s1, s2, s3, s4, buf1, i, j, lane);
    __syncthreads();
    // L4: halves at waves 0, 8
    if (w == 8) stage_fat(buf0, s1, s2, s3, s4, lane);
    __syncthreads();
    if (w == 0) combine_fat(s1, s2, s3, s4, buf0, i, j, lane);
    __syncthreads();
    // final stage: full signature -> buf0 for all waves to read
    if (w == 0) stage_fat(buf0, s1, s2, s3, s4, lane);
    __syncthreads();

    // ---- Phase 3: fused linear (verified epilogue; threads 0..511 only)
    if (t < 512) {
        const int ij = t >> 3, kk = t & 7;
        const float myA3 = buf0[B3OFF + ij * 9 + kk];
        float myA4[8];
        #pragma unroll
        for (int l = 0; l < 8; ++l) myA4[l] = buf0[B4OFF + ij * 65 + kk * 8 + l];
        const float myA2 = buf0[B2OFF + ij];    // canonical owner: kk == 0
        const float myA1 = buf0[t >> 6];        // canonical owner: (t&63) == 0

        float part[N_OUT];
        #pragma unroll
        for (int n = 0; n < N_OUT; ++n) {
            const float* __restrict__ Wn = W + (size_t)n * SIG_DIM;
            float p = myA3 * Wn[OFF3W + t];
            const float4 w4a = *(const float4*)&Wn[OFF4W + t * 8];
            const float4 w4b = *(const float4*)&Wn[OFF4W + t * 8 + 4];
            p = fmaf(myA4[0], w4a.x, p);
            p = fmaf(myA4[1], w4a.y, p);
            p = fmaf(myA4[2], w4a.z, p);
            p = fmaf(myA4[3], w4a.w, p);
            p = fmaf(myA4[4], w4b.x, p);
            p = fmaf(myA4[5], w4b.y, p);
            p = fmaf(myA4[6], w4b.z, p);
            p = fmaf(myA4[7], w4b.w, p);
            if ((t & 7) == 0)  p = fmaf(myA2, Wn[OFF2W + (t >> 3)], p);
            if ((t & 63) == 0) p = fmaf(myA1, Wn[t >> 6], p);
            part[n] = p;
        }

        // wave reduce (64 lanes), then lane 0 deposits
        #pragma unroll
        for (int n = 0; n < N_OUT; ++n) {
            #pragma unroll
            for (int off = 32; off > 0; off >>= 1)
                part[n] += __shfl_xor(part[n], off, 64);
        }
        if (lane == 0) {
            #pragma unroll
            for (int n = 0; n < N_OUT; ++n) red[w][n] = part[n];
        }
    }
    __syncthreads();
    if (t < N_OUT) {
        float s = bias[t];
        #pragma unroll
        for (int q = 0; q < 8; ++q) s += red[q][t];
        out[b * N_OUT + t] = s;
    }
}

extern "C" void kernel_launch(void* const* d_in, const int* in_sizes, int n_in,
                              void* d_out, int out_size, void* d_ws, size_t ws_size,
                              hipStream_t stream) {
    const float* X    = (const float*)d_in[0];
    const float* W    = (const float*)d_in[1];
    const float* bias = (const float*)d_in[2];
    float* out = (float*)d_out;
    (void)d_ws; (void)ws_size;

    hipLaunchKernelGGL(sig_fused_kernel, dim3(BATCH), dim3(1024), 0, stream,
                       X, W, bias, out);
}

// Round 20
// 31.138 us; speedup vs baseline: 1.4028x; 1.4028x over previous
//
#include <hip/hip_runtime.h>

#define BATCH 128
#define LEN 512
#define SIG_DIM 4680          // 8 + 64 + 512 + 4096
#define N_OUT 10
// thin sig offsets (global layout, W indexing)
#define OFF2 8
#define OFF3 72
#define OFF4 584
// FATPAD LDS signature buffer: B1[8] | B2[64] | B3[64x9 pad] | B4[64x65 pad]
#define B2OFF 8
#define B3OFF 72
#define B4OFF 648
#define BUFSZ 4808

typedef float v4f __attribute__((ext_vector_type(4)));

// stage a fat-layout signature (lane=(i,j) owns s2, s3[k], s4[k][l]) into a
// FATPAD LDS buffer. [R16-verified]
__device__ __forceinline__ void stage_fat(float* __restrict__ buf,
                                          float s1, float s2,
                                          const float s3[8], const float s4[8][8],
                                          int lane) {
    if ((lane & 7) == 0) buf[lane >> 3] = s1;          // B1[i] (j==0 canonical)
    buf[B2OFF + lane] = s2;                            // B2[ij]
    #pragma unroll
    for (int k = 0; k < 8; ++k) buf[B3OFF + lane * 9 + k] = s3[k];
    #pragma unroll
    for (int k = 0; k < 8; ++k) {
        #pragma unroll
        for (int l = 0; l < 8; ++l)
            buf[B4OFF + lane * 65 + k * 8 + l] = s4[k][l];
    }
}

// Chen combine in fat layout: A (regs, earlier chunk) ∘= B (FATPAD LDS).
// [R16-verified]
__device__ __forceinline__ void combine_fat(float& A1, float& A2,
                                            float A3[8], float A4[8][8],
                                            const float* __restrict__ buf,
                                            int i, int j, int lane) {
    float B1[8];
    #pragma unroll
    for (int l = 0; l < 8; ++l) B1[l] = buf[l];
    #pragma unroll
    for (int k = 0; k < 8; ++k) {
        #pragma unroll
        for (int l = 0; l < 8; ++l) {
            A4[k][l] += A3[k] * B1[l]
                      + A2 * buf[B2OFF + k * 8 + l]
                      + A1 * buf[B3OFF + (j * 8 + k) * 9 + l]
                      + buf[B4OFF + lane * 65 + k * 8 + l];
        }
    }
    #pragma unroll
    for (int k = 0; k < 8; ++k) {
        A3[k] += A2 * B1[k]
               + A1 * buf[B2OFF + j * 8 + k]
               + buf[B3OFF + lane * 9 + k];
    }
    A2 += A1 * B1[j] + buf[B2OFF + lane];
    A1 += B1[i];
}

// ---------------------------------------------------------------------------
// Kernel 1: one block per (batch, half); 512 thr = 8 waves x 32-step scan.
// Grid 256 -> ALL 256 CUs active (R16 used only 128). Phases: dx->LDS,
// fat scan, 3-level FATPAD tree [all R16/R18-verified], thin half-sig out.
// ---------------------------------------------------------------------------
__global__ __launch_bounds__(512) void sig_half_kernel(const float* __restrict__ X,
                                                       float* __restrict__ sig) {
    const int blk = blockIdx.x;      // b * 2 + h
    const int b = blk >> 1, h = blk & 1;
    const int t = threadIdx.x;
    const int w = t >> 6;            // wave id == sub-chunk id (0..7)
    const int lane = t & 63;
    const int i = lane >> 3, j = lane & 7;
    const int s0base = h * 256;

    __shared__ __align__(16) float lds[4 * BUFSZ];     // 75.1 KB (dx reuses it)

    // ---- Phase 0: dx rows [s0base, s0base+256) -> lds[0..2047] (8 KB)
    {
        const float2* __restrict__ X2 =
            (const float2*)(X + ((size_t)b * LEN + s0base) * 8);
        float2* __restrict__ d2 = (float2*)lds;
        #pragma unroll
        for (int p = 0; p < 2; ++p) {
            const int q = t + p * 512;                 // float2 idx 0..1023
            float2 r = make_float2(0.f, 0.f);
            if (s0base + (q >> 2) < LEN - 1) {         // guard global row 511
                const float2 a = X2[q], c = X2[q + 4];
                r = make_float2(c.x - a.x, c.y - a.y);
            }
            d2[q] = r;
        }
    }
    __syncthreads();

    // ---- Phase 1: fat scan; wave w scans steps [s0, s0+nst)
    float s1 = 0.f, s2 = 0.f;
    float s3[8] = {};
    float s4[8][8] = {};
    {
        const int s0 = s0base + w * 32;
        const int nst = (s0 + 32 <= LEN - 1) ? 32 : (LEN - 1 - s0);  // 31 last
        const v4f* __restrict__ Xv = (const v4f*)(X + (size_t)b * LEN * 8);
        v4f pA = Xv[s0 * 2], pB = Xv[s0 * 2 + 1];
        const v4f* __restrict__ Xn = Xv + (s0 + 1) * 2;
        const float* __restrict__ dxL = lds + (w * 32) * 8;
        #pragma unroll 4
        for (int s = 0; s < nst; ++s) {
            const v4f cA = Xn[s * 2], cB = Xn[s * 2 + 1];   // uniform VMEM
            const v4f dA = cA - pA, dB = cB - pB;
            pA = cA; pB = cB;
            const float vi = dxL[s * 8 + i];           // LDS broadcast
            const float vj = dxL[s * 8 + j];
            const float dv[8] = {dA.x, dA.y, dA.z, dA.w, dB.x, dB.y, dB.z, dB.w};

            const float t1 = s1 * vj;
            const float p  = vi * vj;
            const float u  = fmaf(1.f / 24.f, p, fmaf(1.f / 6.f, t1, 0.5f * s2));
            const float ww = fmaf(1.f / 6.f, p, fmaf(0.5f, t1, s2));
            float cc[8];
            #pragma unroll
            for (int k = 0; k < 8; ++k) {
                cc[k] = fmaf(dv[k], u, s3[k]);
                s3[k] = fmaf(dv[k], ww, s3[k]);
            }
            #pragma unroll
            for (int k = 0; k < 8; ++k) {
                #pragma unroll
                for (int l = 0; l < 8; ++l)
                    s4[k][l] = fmaf(cc[k], dv[l], s4[k][l]);
            }
            s2 = fmaf(0.5f, p, s2 + t1);
            s1 += vi;
        }
    }
    __syncthreads();            // dx region dead; lds becomes 4 sig buffers

    float* __restrict__ buf0 = lds;
    float* __restrict__ buf1 = lds + BUFSZ;
    float* __restrict__ buf2 = lds + 2 * BUFSZ;
    float* __restrict__ buf3 = lds + 3 * BUFSZ;

    // ---- Phase 2: 3-level pairwise Chen tree [R16-verified schedule]
    if (w == 1) stage_fat(buf0, s1, s2, s3, s4, lane);
    if (w == 3) stage_fat(buf1, s1, s2, s3, s4, lane);
    if (w == 5) stage_fat(buf2, s1, s2, s3, s4, lane);
    if (w == 7) stage_fat(buf3, s1, s2, s3, s4, lane);
    __syncthreads();
    if (w == 0) combine_fat(s1, s2, s3, s4, buf0, i, j, lane);
    if (w == 2) combine_fat(s1, s2, s3, s4, buf1, i, j, lane);
    if (w == 4) combine_fat(s1, s2, s3, s4, buf2, i, j, lane);
    if (w == 6) combine_fat(s1, s2, s3, s4, buf3, i, j, lane);
    __syncthreads();
    if (w == 2) stage_fat(buf0, s1, s2, s3, s4, lane);
    if (w == 6) stage_fat(buf1, s1, s2, s3, s4, lane);
    __syncthreads();
    if (w == 0) combine_fat(s1, s2, s3, s4, buf0, i, j, lane);
    if (w == 4) combine_fat(s1, s2, s3, s4, buf1, i, j, lane);
    __syncthreads();
    if (w == 4) stage_fat(buf0, s1, s2, s3, s4, lane);
    __syncthreads();
    if (w == 0) combine_fat(s1, s2, s3, s4, buf0, i, j, lane);
    __syncthreads();
    if (w == 0) stage_fat(buf0, s1, s2, s3, s4, lane);
    __syncthreads();

    // ---- Phase 3: write half-sig THIN to global [R18-verified]
    float* __restrict__ o = sig + (size_t)blk * SIG_DIM;
    const int ij = t >> 3, kk = t & 7;
    if (t < 8)  o[t] = buf0[t];
    if (t < 64) o[OFF2 + t] = buf0[B2OFF + t];
    o[OFF3 + t] = buf0[B3OFF + ij * 9 + kk];
    {
        const float* __restrict__ src = &buf0[B4OFF + ij * 65 + kk * 8];
        *(float4*)&o[OFF4 + t * 8] =
            make_float4(src[0], src[1], src[2], src[3]);
        *(float4*)&o[OFF4 + t * 8 + 4] =
            make_float4(src[4], src[5], src[6], src[7]);
    }
}

// ---------------------------------------------------------------------------
// Kernel 2 [R8-verified verbatim]: ONE Chen-combine (half0 x half1) straight
// from global + fused linear + block reduction. 128 blocks x 512 threads.
// ---------------------------------------------------------------------------
__global__ __launch_bounds__(512) void sig_combine_linear(const float* __restrict__ sig,
                                                          const float* __restrict__ W,
                                                          const float* __restrict__ bias,
                                                          float* __restrict__ out) {
    const int b = blockIdx.x;
    const int t = threadIdx.x;
    const int i = t >> 6, j = (t >> 3) & 7, k = t & 7;
    const float* __restrict__ A = sig + (size_t)(b * 2) * SIG_DIM;   // half 0
    const float* __restrict__ B = A + SIG_DIM;                       // half 1

    float A1 = A[i];
    float A2 = A[OFF2 + i * 8 + j];
    float A3 = A[OFF3 + t];
    const float4 a4a = *(const float4*)&A[OFF4 + t * 8];
    const float4 a4b = *(const float4*)&A[OFF4 + t * 8 + 4];
    float A4[8] = {a4a.x, a4a.y, a4a.z, a4a.w, a4b.x, a4b.y, a4b.z, a4b.w};

    const float B1i = B[i], B1j = B[j], B1k = B[k];
    const float4 b1a = *(const float4*)&B[0];
    const float4 b1b = *(const float4*)&B[4];
    const float B2ij = B[OFF2 + i * 8 + j];
    const float B2jk = B[OFF2 + j * 8 + k];
    const float4 b2a = *(const float4*)&B[OFF2 + k * 8];
    const float4 b2b = *(const float4*)&B[OFF2 + k * 8 + 4];
    const float B3ijk = B[OFF3 + t];
    const float4 b3a = *(const float4*)&B[OFF3 + (j * 8 + k) * 8];
    const float4 b3b = *(const float4*)&B[OFF3 + (j * 8 + k) * 8 + 4];
    const float4 b4a = *(const float4*)&B[OFF4 + t * 8];
    const float4 b4b = *(const float4*)&B[OFF4 + t * 8 + 4];

    A4[0] += A3 * b1a.x + A2 * b2a.x + A1 * b3a.x + b4a.x;
    A4[1] += A3 * b1a.y + A2 * b2a.y + A1 * b3a.y + b4a.y;
    A4[2] += A3 * b1a.z + A2 * b2a.z + A1 * b3a.z + b4a.z;
    A4[3] += A3 * b1a.w + A2 * b2a.w + A1 * b3a.w + b4a.w;
    A4[4] += A3 * b1b.x + A2 * b2b.x + A1 * b3b.x + b4b.x;
    A4[5] += A3 * b1b.y + A2 * b2b.y + A1 * b3b.y + b4b.y;
    A4[6] += A3 * b1b.z + A2 * b2b.z + A1 * b3b.z + b4b.z;
    A4[7] += A3 * b1b.w + A2 * b2b.w + A1 * b3b.w + b4b.w;
    A3 += A2 * B1k + A1 * B2jk + B3ijk;
    A2 += A1 * B1j + B2ij;
    A1 += B1i;

    // Fused linear: out[b][n] = sum_d sig[d] * W[n][d] + bias[n]
    float part[N_OUT];
    #pragma unroll
    for (int n = 0; n < N_OUT; ++n) {
        const float* __restrict__ Wn = W + (size_t)n * SIG_DIM;
        float p = A3 * Wn[OFF3 + t];
        const float4 w4a = *(const float4*)&Wn[OFF4 + t * 8];
        const float4 w4b = *(const float4*)&Wn[OFF4 + t * 8 + 4];
        p = fmaf(A4[0], w4a.x, p);
        p = fmaf(A4[1], w4a.y, p);
        p = fmaf(A4[2], w4a.z, p);
        p = fmaf(A4[3], w4a.w, p);
        p = fmaf(A4[4], w4b.x, p);
        p = fmaf(A4[5], w4b.y, p);
        p = fmaf(A4[6], w4b.z, p);
        p = fmaf(A4[7], w4b.w, p);
        if ((t & 7) == 0)  p = fmaf(A2, Wn[OFF2 + (t >> 3)], p);
        if ((t & 63) == 0) p = fmaf(A1, Wn[t >> 6], p);
        part[n] = p;
    }

    #pragma unroll
    for (int n = 0; n < N_OUT; ++n) {
        #pragma unroll
        for (int off = 32; off > 0; off >>= 1)
            part[n] += __shfl_xor(part[n], off, 64);
    }
    __shared__ float red[8][N_OUT];
    const int wv = t >> 6, ln = t & 63;
    if (ln == 0) {
        #pragma unroll
        for (int n = 0; n < N_OUT; ++n) red[wv][n] = part[n];
    }
    __syncthreads();
    if (t < N_OUT) {
        float s = bias[t];
        #pragma unroll
        for (int w = 0; w < 8; ++w) s += red[w][t];
        out[b * N_OUT + t] = s;
    }
}

extern "C" void kernel_launch(void* const* d_in, const int* in_sizes, int n_in,
                              void* d_out, int out_size, void* d_ws, size_t ws_size,
                              hipStream_t stream) {
    const float* X    = (const float*)d_in[0];
    const float* W    = (const float*)d_in[1];
    const float* bias = (const float*)d_in[2];
    float* out = (float*)d_out;
    float* sig = (float*)d_ws;                 // 256*SIG_DIM*4 ≈ 4.8 MB

    hipLaunchKernelGGL(sig_half_kernel, dim3(BATCH * 2), dim3(512), 0, stream, X, sig);
    hipLaunchKernelGGL(sig_combine_linear, dim3(BATCH), dim3(512), 0, stream, sig, W, bias, out);
}